// Round 1
// baseline (271.614 us; speedup 1.0000x reference)
//
#include <hip/hip_runtime.h>
#include <hip/hip_bf16.h>

typedef short s8v __attribute__((ext_vector_type(8)));
typedef short s4v __attribute__((ext_vector_type(4)));
typedef float f4v __attribute__((ext_vector_type(4)));

#define DEV __device__ __forceinline__

DEV unsigned short f2b(float f) {
  unsigned u = __builtin_bit_cast(unsigned, f);
  u += 0x7FFFu + ((u >> 16) & 1u);
  return (unsigned short)(u >> 16);
}
DEV float b2f(unsigned short s) {
  unsigned u = ((unsigned)s) << 16;
  return __builtin_bit_cast(float, u);
}
DEV float sigf(float x) { return __builtin_amdgcn_rcpf(1.f + __expf(-x)); }
DEV float tanhf_(float x) { return 1.f - 2.f * __builtin_amdgcn_rcpf(__expf(2.f * x) + 1.f); }

// ---------------- workspace layout (bytes, all 256-aligned) ----------------
#define O_WHH0  0u          // 131072  bf16 frag-packed whh0
#define O_WHH1  131072u     // 131072
#define O_WIH0  262144u     // 65536
#define O_WIH1  327680u     // 131072
#define O_B0    458752u     // 2048    f32 permuted bih0+bhh0
#define O_B1    460800u     // 2048
#define O_WA    462848u     // 8192    f32 folded comb_w[:, :64] @ de_w2  (64x32)
#define O_EMB2  471040u     // 4096    f32 embed @ comb_w[:,64:80]^T     (16x64)
#define O_BC    475136u     // 256     f32 comb_b + comb_w[:,:64]@de_b2  (64)
#define O_DP1T  475392u     // 32768   bf16 dp_w1^T  [k][d] 128x128
#define O_CP1T  508160u     // 16384   bf16 cp_w1^T  [k][d] 128x64
#define O_PC1T  524544u     // 8192    bf16 pc_w1^T  [k][d] 128x32
#define O_DP2T  532736u     // 4096    f32 dp_w2^T [k][o] 128x8
#define O_CP2T  536832u     // 2048    f32 cp_w2^T 64x8
#define O_PC2T  538880u     // 512     f32 pc_w2^T 32x4
#define O_HFIN  539392u     // 4194304 f32 h_final [8192][128]
#define O_FEATS 4733696u    // 33554432 bf16 feats [blk][t][row32][64]
#define O_Y0    38288128u   // 67108864 bf16 y0    [blk][t][row32][128]

// Column permutation: reordered col c (0..511) -> orig gate-major row of W.
// wave w = c>>6 owns h-dims [16w,16w+16); clocal = 16*gate + dl.
DEV int orig_col(int c) { return 128 * ((c >> 4) & 3) + 16 * (c >> 6) + (c & 15); }

// =============================== prep ===============================
__global__ void prep_kernel(
    const float* de_w1, const float* de_b1, const float* de_w2, const float* de_b2,
    const float* embed, const float* comb_w, const float* comb_b,
    const float* w0ih, const float* w0hh, const float* b0ih, const float* b0hh,
    const float* w1ih, const float* w1hh, const float* b1ih, const float* b1hh,
    const float* dp_w1, const float* dp_w2, const float* cp_w1, const float* cp_w2,
    const float* pc_w1, const float* pc_w2, char* ws)
{
  unsigned short* wih0p = (unsigned short*)(ws + O_WIH0);
  unsigned short* whh0p = (unsigned short*)(ws + O_WHH0);
  unsigned short* wih1p = (unsigned short*)(ws + O_WIH1);
  unsigned short* whh1p = (unsigned short*)(ws + O_WHH1);
  float* b0p = (float*)(ws + O_B0);
  float* b1p = (float*)(ws + O_B1);
  float* Wa  = (float*)(ws + O_WA);
  float* bc  = (float*)(ws + O_BC);
  float* em2 = (float*)(ws + O_EMB2);
  unsigned short* dp1t = (unsigned short*)(ws + O_DP1T);
  unsigned short* cp1t = (unsigned short*)(ws + O_CP1T);
  unsigned short* pc1t = (unsigned short*)(ws + O_PC1T);
  float* dp2t = (float*)(ws + O_DP2T);
  float* cp2t = (float*)(ws + O_CP2T);
  float* pc2t = (float*)(ws + O_PC2T);

  const int T0 = 32768, T1 = T0 + 65536, T2 = T1 + 65536, T3 = T2 + 65536,
            T4 = T3 + 512, T5 = T4 + 512, T6 = T5 + 2048, T7 = T6 + 64,
            T8 = T7 + 1024, T9 = T8 + 16384, T10 = T9 + 8192, T11 = T10 + 4096,
            T12 = T11 + 1024, T13 = T12 + 512, T14 = T13 + 128;

  for (int idx = blockIdx.x * 256 + threadIdx.x; idx < T14; idx += gridDim.x * 256) {
    if (idx < T3) {  // fragment packing
      int u, Kin; const float* src; unsigned short* dst;
      if (idx < T0)      { u = idx;      Kin = 64;  src = w0ih; dst = wih0p; }
      else if (idx < T1) { u = idx - T0; Kin = 128; src = w0hh; dst = whh0p; }
      else if (idx < T2) { u = idx - T1; Kin = 128; src = w1ih; dst = wih1p; }
      else               { u = idx - T2; Kin = 128; src = w1hh; dst = whh1p; }
      int j = u & 7, l = (u >> 3) & 63, nt = (u >> 9) & 31, kt = u >> 14;
      int c = 16 * nt + (l & 15);
      int k = 32 * kt + 8 * (l >> 4) + j;
      dst[u] = f2b(src[orig_col(c) * Kin + k]);
    } else if (idx < T5) {  // permuted biases
      int u = idx - T3;
      if (u < 512) b0p[u] = b0ih[orig_col(u)] + b0hh[orig_col(u)];
      else { int c = u - 512; b1p[c] = b1ih[orig_col(c)] + b1hh[orig_col(c)]; }
    } else if (idx < T6) {  // W_a[f][kk] = sum_f2 comb_w[f][f2]*de_w2[f2][kk]
      int u = idx - T5, f = u >> 5, kk = u & 31;
      float a = 0.f;
      for (int f2 = 0; f2 < 64; f2++) a += comb_w[f * 80 + f2] * de_w2[f2 * 32 + kk];
      Wa[u] = a;
    } else if (idx < T7) {  // b_comb
      int f = idx - T6;
      float a = comb_b[f];
      for (int f2 = 0; f2 < 64; f2++) a += comb_w[f * 80 + f2] * de_b2[f2];
      bc[f] = a;
    } else if (idx < T8) {  // emb2[e][f]
      int u = idx - T7, e = u >> 6, f = u & 63;
      float a = 0.f;
      for (int j = 0; j < 16; j++) a += embed[e * 16 + j] * comb_w[f * 80 + 64 + j];
      em2[u] = a;
    } else if (idx < T9)  { int u = idx - T8;  int k = u >> 7, d = u & 127; dp1t[u] = f2b(dp_w1[d * 128 + k]); }
    else if (idx < T10)   { int u = idx - T9;  int k = u >> 6, d = u & 63;  cp1t[u] = f2b(cp_w1[d * 128 + k]); }
    else if (idx < T11)   { int u = idx - T10; int k = u >> 5, d = u & 31;  pc1t[u] = f2b(pc_w1[d * 128 + k]); }
    else if (idx < T12)   { int u = idx - T11; int k = u >> 3, o = u & 7;   dp2t[u] = dp_w2[o * 128 + k]; }
    else if (idx < T13)   { int u = idx - T12; int k = u >> 3, o = u & 7;   cp2t[u] = cp_w2[o * 64 + k]; }
    else                  { int u = idx - T13; int k = u >> 2, o = u & 3;   pc2t[u] = pc_w2[o * 32 + k]; }
  }
}

// =============================== frontend ===============================
__global__ __launch_bounds__(256) void frontend_kernel(
    const float* __restrict__ x_feat, const int* __restrict__ acc_t,
    const float* __restrict__ de_w1, const float* __restrict__ de_b1,
    const char* __restrict__ ws, unsigned short* __restrict__ feats)
{
  __shared__ float sW1[256], sB1[32], sWa[2048], sBc[64], sE2[1024];
  const float* Wa  = (const float*)(ws + O_WA);
  const float* bc  = (const float*)(ws + O_BC);
  const float* em2 = (const float*)(ws + O_EMB2);
  int tid = threadIdx.x;
  sW1[tid] = de_w1[tid];
  if (tid < 32) sB1[tid] = de_b1[tid];
  for (int i = tid; i < 2048; i += 256) sWa[i] = Wa[i];
  if (tid < 64) sBc[tid] = bc[tid];
  for (int i = tid; i < 1024; i += 256) sE2[i] = em2[i];
  __syncthreads();

  int g = blockIdx.x * 256 + tid;  // g = b*32 + t
  f4v x0 = ((const f4v*)(x_feat + (size_t)g * 8))[0];
  f4v x1 = ((const f4v*)(x_feat + (size_t)g * 8))[1];
  float xs[8];
#pragma unroll
  for (int i = 0; i < 4; i++) { xs[i] = x0[i]; xs[4 + i] = x1[i]; }
  int at = acc_t[g];

  float r1[32];
#pragma unroll
  for (int kk = 0; kk < 32; kk++) {
    float a = sB1[kk];
#pragma unroll
    for (int i = 0; i < 8; i++) a += xs[i] * sW1[kk * 8 + i];
    r1[kk] = fmaxf(a, 0.f);
  }
  int b = g >> 5, t = g & 31;
  unsigned short* dst = feats + (size_t)((b >> 5) * 1024 + t * 32 + (b & 31)) * 64;
  for (int j8 = 0; j8 < 8; j8++) {
    s8v pack;
#pragma unroll
    for (int jj = 0; jj < 8; jj++) {
      int j = j8 * 8 + jj;
      float a = sBc[j] + sE2[at * 64 + j];
#pragma unroll
      for (int kk = 0; kk < 32; kk++) a += r1[kk] * sWa[j * 32 + kk];
      pack[jj] = (short)f2b(a);
    }
    *(s8v*)(dst + j8 * 8) = pack;
  }
}

// =============================== main LSTM ===============================
template <int PASS>
DEV void run_pass(int tid, int blk,
                  const unsigned short* __restrict__ whhp,
                  const unsigned short* __restrict__ wihp,
                  const float* __restrict__ bp,
                  const unsigned short* __restrict__ inglob,
                  unsigned short* __restrict__ y0buf,
                  float* __restrict__ hfinal,
                  unsigned short* sWhh, unsigned short* sIn,
                  unsigned short* sH0, unsigned short* sH1)
{
  constexpr int KIN = PASS ? 128 : 64;
  constexpr int NKT = KIN / 32;
  const int w = tid >> 6, l = tid & 63, l15 = l & 15, lhi = l >> 4;

  // stage whh fragments into LDS (linear, pre-packed)
  for (int i = tid; i < 8192; i += 512)
    *(s8v*)(sWhh + i * 8) = *(const s8v*)(whhp + i * 8);
  // zero h buffer 0
  {
    s8v z = {0, 0, 0, 0, 0, 0, 0, 0};
    *(s8v*)(sH0 + tid * 8) = z;
  }
  // wih fragments -> registers
  s8v wf[NKT][4];
#pragma unroll
  for (int kt = 0; kt < NKT; kt++)
#pragma unroll
    for (int gg = 0; gg < 4; gg++)
      wf[kt][gg] = *(const s8v*)(wihp + (size_t)((kt * 32 + (4 * w + gg)) * 64 + l) * 8);
  float bias_[4];
#pragma unroll
  for (int gg = 0; gg < 4; gg++) bias_[gg] = bp[64 * w + 16 * gg + l15];
  float cst[2][4] = {{0, 0, 0, 0}, {0, 0, 0, 0}};

  // prefetch tile 0
  s8v pre8; s4v pre4;
  if constexpr (PASS == 0) pre4 = *(const s4v*)(inglob + (size_t)blk * 65536 + tid * 4);
  else                     pre8 = *(const s8v*)(inglob + (size_t)blk * 131072 + tid * 8);
  __syncthreads();

  const int srow = tid >> 4;
  const int sswz = (srow & 7) << 4;
  char* sInB = (char*)sIn;
  const int d = 16 * w + l15;

  for (int t = 0; t < 32; ++t) {
    // stage current tile into sIn (XOR-swizzled rows)
    if constexpr (PASS == 0)
      *(s4v*)(sInB + srow * 128 + (((tid & 15) * 8) ^ sswz)) = pre4;
    else
      *(s8v*)(sInB + srow * 256 + (((tid & 15) * 16) ^ sswz)) = pre8;
    if (t < 31) {
      if constexpr (PASS == 0)
        pre4 = *(const s4v*)(inglob + (size_t)blk * 65536 + (t + 1) * 2048 + tid * 4);
      else
        pre8 = *(const s8v*)(inglob + (size_t)blk * 131072 + (t + 1) * 4096 + tid * 8);
    }
    __syncthreads();

    f4v acc[2][4];
#pragma unroll
    for (int mt = 0; mt < 2; mt++)
#pragma unroll
      for (int gg = 0; gg < 4; gg++)
        acc[mt][gg] = f4v{bias_[gg], bias_[gg], bias_[gg], bias_[gg]};

    // input contribution: A = in-tile, B = wih (regs)
#pragma unroll
    for (int kt = 0; kt < NKT; kt++) {
#pragma unroll
      for (int mt = 0; mt < 2; mt++) {
        int row = 16 * mt + l15;
        int kb = (kt * 32 + 8 * lhi) * 2;
        s8v a = *(const s8v*)(sInB + row * (KIN * 2) + (kb ^ ((row & 7) << 4)));
#pragma unroll
        for (int gg = 0; gg < 4; gg++)
          acc[mt][gg] = __builtin_amdgcn_mfma_f32_16x16x32_bf16(a, wf[kt][gg], acc[mt][gg], 0, 0, 0);
      }
    }
    // recurrent contribution: A = h (LDS dbuf), B = whh (LDS)
    const char* hb = (const char*)((t & 1) ? sH1 : sH0);
#pragma unroll
    for (int kt = 0; kt < 4; kt++) {
      s8v bf[4];
#pragma unroll
      for (int gg = 0; gg < 4; gg++)
        bf[gg] = *(const s8v*)(sWhh + (size_t)((kt * 32 + 4 * w + gg) * 64 + l) * 8);
#pragma unroll
      for (int mt = 0; mt < 2; mt++) {
        int row = 16 * mt + l15;
        int kb = (kt * 32 + 8 * lhi) * 2;
        s8v a = *(const s8v*)(hb + row * 256 + (kb ^ ((row & 7) << 4)));
#pragma unroll
        for (int gg = 0; gg < 4; gg++)
          acc[mt][gg] = __builtin_amdgcn_mfma_f32_16x16x32_bf16(a, bf[gg], acc[mt][gg], 0, 0, 0);
      }
    }
    // pointwise LSTM cell: lane owns dim d, rows 16mt+4lhi+r
    char* hn = (char*)((t & 1) ? sH0 : sH1);
#pragma unroll
    for (int mt = 0; mt < 2; mt++) {
#pragma unroll
      for (int r = 0; r < 4; r++) {
        float iv = sigf(acc[mt][0][r]);
        float fv = sigf(acc[mt][1][r]);
        float gv = tanhf_(acc[mt][2][r]);
        float ov = sigf(acc[mt][3][r]);
        float cv = fv * cst[mt][r] + iv * gv;
        cst[mt][r] = cv;
        float hv = ov * tanhf_(cv);
        int row = 16 * mt + 4 * lhi + r;
        unsigned short hq = f2b(hv);
        *(unsigned short*)(hn + row * 256 + ((d * 2) ^ ((row & 7) << 4))) = hq;
        if constexpr (PASS == 0)
          y0buf[(size_t)blk * 131072 + t * 4096 + row * 128 + d] = hq;
        else if (t == 31)
          hfinal[(size_t)(blk * 32 + row) * 128 + d] = hv;
      }
    }
    __syncthreads();
  }
}

__global__ __launch_bounds__(512, 2) void lstm_main(const char* __restrict__ ws_c, char* __restrict__ ws)
{
  __shared__ __align__(16) unsigned short sWhh[65536];
  __shared__ __align__(16) unsigned short sIn[4096];
  __shared__ __align__(16) unsigned short sH0[4096];
  __shared__ __align__(16) unsigned short sH1[4096];
  int tid = threadIdx.x, blk = blockIdx.x;
  run_pass<0>(tid, blk,
              (const unsigned short*)(ws_c + O_WHH0), (const unsigned short*)(ws_c + O_WIH0),
              (const float*)(ws_c + O_B0),
              (const unsigned short*)(ws_c + O_FEATS),
              (unsigned short*)(ws + O_Y0), nullptr,
              sWhh, sIn, sH0, sH1);
  __syncthreads();
  run_pass<1>(tid, blk,
              (const unsigned short*)(ws_c + O_WHH1), (const unsigned short*)(ws_c + O_WIH1),
              (const float*)(ws_c + O_B1),
              (const unsigned short*)(ws_c + O_Y0),
              nullptr, (float*)(ws + O_HFIN),
              sWhh, sIn, sH0, sH1);
}

// =============================== heads ===============================
__global__ __launch_bounds__(256) void heads_kernel(
    const char* __restrict__ ws,
    const float* __restrict__ dp_b1, const float* __restrict__ dp_b2,
    const float* __restrict__ cp_b1, const float* __restrict__ cp_b2,
    const float* __restrict__ pc_b1, const float* __restrict__ pc_b2,
    float* __restrict__ out)
{
  __shared__ __align__(16) float sh[4096];
  __shared__ __align__(16) unsigned short sw1[28672];
  __shared__ __align__(16) float smid[7168];
  __shared__ __align__(16) float sw2[1664];
  __shared__ float spc[128];
  const float* hfinal = (const float*)(ws + O_HFIN);
  const unsigned short* dp1t = (const unsigned short*)(ws + O_DP1T);
  const unsigned short* cp1t = (const unsigned short*)(ws + O_CP1T);
  const unsigned short* pc1t = (const unsigned short*)(ws + O_PC1T);
  const float* dp2t = (const float*)(ws + O_DP2T);
  const float* cp2t = (const float*)(ws + O_CP2T);
  const float* pc2t = (const float*)(ws + O_PC2T);
  int tid = threadIdx.x, blk = blockIdx.x;

  for (int i = tid; i < 1024; i += 256)
    *(f4v*)(sh + i * 4) = *(const f4v*)(hfinal + (size_t)blk * 4096 + i * 4);
  for (int i = tid; i < 2048; i += 256) *(s8v*)(sw1 + i * 8) = *(const s8v*)(dp1t + i * 8);
  for (int i = tid; i < 1024; i += 256) *(s8v*)(sw1 + 16384 + i * 8) = *(const s8v*)(cp1t + i * 8);
  for (int i = tid; i < 512;  i += 256) *(s8v*)(sw1 + 24576 + i * 8) = *(const s8v*)(pc1t + i * 8);
  for (int i = tid; i < 1024; i += 256) sw2[i] = dp2t[i];
  for (int i = tid; i < 512;  i += 256) sw2[1024 + i] = cp2t[i];
  for (int i = tid; i < 128;  i += 256) sw2[1536 + i] = pc2t[i];
  __syncthreads();

  for (int i = tid; i < 7168; i += 256) {
    int row = i / 224, md = i - row * 224;
    float a;
    if (md < 128) {
      a = dp_b1[md];
      for (int k = 0; k < 128; k++) a += sh[row * 128 + k] * b2f(sw1[k * 128 + md]);
    } else if (md < 192) {
      int dd = md - 128; a = cp_b1[dd];
      for (int k = 0; k < 128; k++) a += sh[row * 128 + k] * b2f(sw1[16384 + k * 64 + dd]);
    } else {
      int dd = md - 192; a = pc_b1[dd];
      for (int k = 0; k < 128; k++) a += sh[row * 128 + k] * b2f(sw1[24576 + k * 32 + dd]);
    }
    smid[i] = fmaxf(a, 0.f);
  }
  __syncthreads();

  for (int i = tid; i < 640; i += 256) {
    int row = i / 20, o = i - row * 20;
    if (o < 8) {
      float a = dp_b2[o];
      for (int k = 0; k < 128; k++) a += smid[row * 224 + k] * sw2[k * 8 + o];
      out[(size_t)(blk * 32 + row) * 20 + o] = a * 1e6f;
    } else if (o < 16) {
      int oo = o - 8; float a = cp_b2[oo];
      for (int k = 0; k < 64; k++) a += smid[row * 224 + 128 + k] * sw2[1024 + k * 8 + oo];
      out[(size_t)(blk * 32 + row) * 20 + o] = sigf(a);
    } else {
      int oo = o - 16; float a = pc_b2[oo];
      for (int k = 0; k < 32; k++) a += smid[row * 224 + 192 + k] * sw2[1536 + k * 4 + oo];
      spc[row * 4 + oo] = a;
    }
  }
  __syncthreads();

  if (tid < 32) {
    int row = tid;
    float v0 = spc[row * 4], v1 = spc[row * 4 + 1], v2 = spc[row * 4 + 2], v3 = spc[row * 4 + 3];
    float m = fmaxf(fmaxf(v0, v1), fmaxf(v2, v3));
    float e0 = __expf(v0 - m), e1 = __expf(v1 - m), e2 = __expf(v2 - m), e3 = __expf(v3 - m);
    float rs = __builtin_amdgcn_rcpf(e0 + e1 + e2 + e3);
    size_t base = (size_t)(blk * 32 + row) * 20 + 16;
    out[base] = e0 * rs; out[base + 1] = e1 * rs; out[base + 2] = e2 * rs; out[base + 3] = e3 * rs;
  }
}

// =============================== launch ===============================
extern "C" void kernel_launch(void* const* d_in, const int* in_sizes, int n_in,
                              void* d_out, int out_size, void* d_ws, size_t ws_size,
                              hipStream_t stream) {
  const float* x_feat = (const float*)d_in[0];
  const int*   acc_t  = (const int*)d_in[1];
  const float* de_w1 = (const float*)d_in[2],  *de_b1 = (const float*)d_in[3];
  const float* de_w2 = (const float*)d_in[4],  *de_b2 = (const float*)d_in[5];
  const float* embed = (const float*)d_in[6];
  const float* comb_w = (const float*)d_in[7], *comb_b = (const float*)d_in[8];
  const float* w0ih = (const float*)d_in[9],  *w0hh = (const float*)d_in[10];
  const float* b0ih = (const float*)d_in[11], *b0hh = (const float*)d_in[12];
  const float* w1ih = (const float*)d_in[13], *w1hh = (const float*)d_in[14];
  const float* b1ih = (const float*)d_in[15], *b1hh = (const float*)d_in[16];
  const float* dp_w1 = (const float*)d_in[17], *dp_b1 = (const float*)d_in[18];
  const float* dp_w2 = (const float*)d_in[19], *dp_b2 = (const float*)d_in[20];
  const float* cp_w1 = (const float*)d_in[21], *cp_b1 = (const float*)d_in[22];
  const float* cp_w2 = (const float*)d_in[23], *cp_b2 = (const float*)d_in[24];
  const float* pc_w1 = (const float*)d_in[25], *pc_b1 = (const float*)d_in[26];
  const float* pc_w2 = (const float*)d_in[27], *pc_b2 = (const float*)d_in[28];
  char* ws = (char*)d_ws;

  prep_kernel<<<256, 256, 0, stream>>>(
      de_w1, de_b1, de_w2, de_b2, embed, comb_w, comb_b,
      w0ih, w0hh, b0ih, b0hh, w1ih, w1hh, b1ih, b1hh,
      dp_w1, dp_w2, cp_w1, cp_w2, pc_w1, pc_w2, ws);

  frontend_kernel<<<1024, 256, 0, stream>>>(
      x_feat, acc_t, de_w1, de_b1, ws, (unsigned short*)(ws + O_FEATS));

  lstm_main<<<256, 512, 0, stream>>>(ws, ws);

  heads_kernel<<<256, 256, 0, stream>>>(
      ws, dp_b1, dp_b2, cp_b1, cp_b2, pc_b1, pc_b2, (float*)d_out);
}